// Round 1
// baseline (1259.573 us; speedup 1.0000x reference)
//
#include <hip/hip_runtime.h>
#include <stdint.h>
#include <math.h>

#define T_TOK 8192
#define DIM   2048
#define OUTD  2048
#define NEXP  8

typedef __bf16 bf16x8 __attribute__((ext_vector_type(8)));
typedef float  f32x4  __attribute__((ext_vector_type(4)));

// ---- bf16 helpers (manual RNE, bit-exact for finite values) ----
__device__ __forceinline__ unsigned short f2bf(float f) {
  union { float f; uint32_t u; } c = {f};
  uint32_t r = (c.u + 0x7FFFu + ((c.u >> 16) & 1u)) >> 16;
  return (unsigned short)r;
}
__device__ __forceinline__ float bf2f(unsigned short h) {
  union { uint32_t u; float f; } c = {((uint32_t)h) << 16};
  return c.f;
}

// ---- async global->LDS 16B (CK-style addrspace casts) ----
__device__ __forceinline__ void gld_lds16(const void* g, void* l) {
  auto gp = reinterpret_cast<const __attribute__((address_space(1))) char*>(
      reinterpret_cast<uintptr_t>(g));
  auto lp = reinterpret_cast<__attribute__((address_space(3))) char*>(
      reinterpret_cast<uintptr_t>(l));
  __builtin_amdgcn_global_load_lds(gp, lp, 16, 0, 0);
}

// ---- split fp32 -> bf16 hi/lo pair ----
__global__ __launch_bounds__(256) void split_hi_lo(const float* __restrict__ src,
                                                   unsigned short* __restrict__ hi,
                                                   unsigned short* __restrict__ lo,
                                                   int n4) {
  int stride = gridDim.x * blockDim.x;
  for (int i = blockIdx.x * blockDim.x + threadIdx.x; i < n4; i += stride) {
    float4 v = reinterpret_cast<const float4*>(src)[i];
    ushort4 h, l;
    h.x = f2bf(v.x); l.x = f2bf(v.x - bf2f(h.x));
    h.y = f2bf(v.y); l.y = f2bf(v.y - bf2f(h.y));
    h.z = f2bf(v.z); l.z = f2bf(v.z - bf2f(h.z));
    h.w = f2bf(v.w); l.w = f2bf(v.w - bf2f(h.w));
    reinterpret_cast<ushort4*>(hi)[i] = h;
    reinterpret_cast<ushort4*>(lo)[i] = l;
  }
}

// ---- router: gate logits (fp64 accum), top-2 (fp32 compare, stable ties),
//      softmax fp32, atomic scatter into per-expert token lists ----
__global__ __launch_bounds__(256) void router(const float* __restrict__ x,
                                              const float* __restrict__ gw,
                                              int* __restrict__ cnt,
                                              int* __restrict__ tok_list,
                                              float* __restrict__ tok_w) {
  const int t    = blockIdx.x * 4 + (threadIdx.x >> 6);  // one wave per token
  const int lane = threadIdx.x & 63;
  const float4* xr = reinterpret_cast<const float4*>(x + (size_t)t * DIM);
  double acc[NEXP];
#pragma unroll
  for (int e = 0; e < NEXP; ++e) acc[e] = 0.0;
#pragma unroll
  for (int i = 0; i < DIM / (4 * 64); ++i) {   // 8 iters
    float4 xv = xr[i * 64 + lane];
#pragma unroll
    for (int e = 0; e < NEXP; ++e) {
      float4 gv = reinterpret_cast<const float4*>(gw + e * DIM)[i * 64 + lane];
      acc[e] += (double)xv.x * gv.x + (double)xv.y * gv.y +
                (double)xv.z * gv.z + (double)xv.w * gv.w;
    }
  }
#pragma unroll
  for (int off = 32; off >= 1; off >>= 1)
#pragma unroll
    for (int e = 0; e < NEXP; ++e) acc[e] += __shfl_down(acc[e], off, 64);
  if (lane == 0) {
    float lg[NEXP];
#pragma unroll
    for (int e = 0; e < NEXP; ++e) lg[e] = (float)acc[e];
    int i0 = 0; float v0 = lg[0];
    int i1 = -1; float v1 = -3.4e38f;
#pragma unroll
    for (int e = 1; e < NEXP; ++e) {
      if (lg[e] > v0)      { i1 = i0; v1 = v0; i0 = e; v0 = lg[e]; }
      else if (lg[e] > v1) { i1 = e;  v1 = lg[e]; }
    }
    float p  = expf(v1 - v0);         // v0 is the max
    float w0 = 1.0f / (1.0f + p);
    float w1 = p * w0;
    int s0 = atomicAdd(&cnt[i0], 1);
    tok_list[i0 * T_TOK + s0] = t; tok_w[i0 * T_TOK + s0] = w0;
    int s1 = atomicAdd(&cnt[i1], 1);
    tok_list[i1 * T_TOK + s1] = t; tok_w[i1 * T_TOK + s1] = w1;
  }
}

// ---- grouped expert GEMM: C[tok][o] += w_tok * (sum_d x[tok][d]*W[e][o][d] + b[e][o])
//      bf16x2 split: xh*wh + xh*wl + xl*wh, fp32 MFMA accum.
//      128x128 tile, BK=64, 4 waves (2x2 of 64x64), global_load_lds staging
//      with XOR-swizzled LDS (pre-swizzled source, swizzled ds_read). ----
__global__ __launch_bounds__(256, 2) void moe_gemm(
    const unsigned short* __restrict__ xh, const unsigned short* __restrict__ xl,
    const unsigned short* __restrict__ wh, const unsigned short* __restrict__ wl,
    const float* __restrict__ eb,
    const int* __restrict__ cnt,
    const int* __restrict__ tok_list, const float* __restrict__ tok_w,
    float* __restrict__ out) {
  const int e  = blockIdx.z;
  const int ce = cnt[e];
  const int bx = blockIdx.x;
  if (bx * 128 >= ce) return;                 // inactive row-block
  const int by  = blockIdx.y;
  const int tid = threadIdx.x;
  const int l   = tid & 63;
  const int w   = tid >> 6;
  const int wr  = w >> 1, wc = w & 1;

  extern __shared__ char smem[];              // 64 KiB: Ah@0 Al@16K Bh@32K Bl@48K
                                              // each tile: 128 rows x 8 phys slots x 16B

  int* stok = reinterpret_cast<int*>(smem);   // transient (overlaps Ah)
  if (tid < 128) {
    int rg = bx * 128 + tid;
    stok[tid] = (rg < ce) ? tok_list[e * T_TOK + rg] : 0;  // pad rows -> token 0
  }
  __syncthreads();

  // staging descriptors: granule g covers LDS bytes [g*16, g*16+16) of a tile;
  // row r = g>>3, phys slot p = g&7 holds logical k-slot s = p ^ (r&7).
  size_t aOff[4], bOff[4];
  int    lOff[4];
#pragma unroll
  for (int i = 0; i < 4; ++i) {
    int g = i * 256 + tid;
    int r = g >> 3, p = g & 7, s = p ^ (r & 7);
    aOff[i] = (size_t)stok[r] * DIM + s * 8;
    bOff[i] = ((size_t)e * OUTD + by * 128 + r) * DIM + s * 8;
    lOff[i] = g * 16;
  }
  __syncthreads();  // all stok reads done before staging overwrites it

  // per-lane ds_read byte offsets (r&7 == l&7 since row low bits come from l&15)
  const int rA = wr * 64 + (l & 15);
  const int rB = wc * 64 + (l & 15);
  const int p0 = ((l >> 4) + 0) ^ (l & 7);    // ks=0: logical slot = l>>4
  const int p1 = ((l >> 4) + 4) ^ (l & 7);    // ks=1: logical slot = 4 + (l>>4)
  const int a0 = rA * 128 + p0 * 16, a1 = rA * 128 + p1 * 16;
  const int b0 = rB * 128 + p0 * 16, b1 = rB * 128 + p1 * 16;

  f32x4 acc[4][4] = {};

  for (int kt = 0; kt < DIM / 64; ++kt) {     // 32 K-tiles
    const int kk = kt * 64;
#pragma unroll
    for (int i = 0; i < 4; ++i) {
      gld_lds16(xh + aOff[i] + kk, smem +         lOff[i]);
      gld_lds16(xl + aOff[i] + kk, smem + 16384 + lOff[i]);
      gld_lds16(wh + bOff[i] + kk, smem + 32768 + lOff[i]);
      gld_lds16(wl + bOff[i] + kk, smem + 49152 + lOff[i]);
    }
    asm volatile("s_waitcnt vmcnt(0)" ::: "memory");
    __syncthreads();

#pragma unroll
    for (int ks = 0; ks < 2; ++ks) {
      const int aB = ks ? a1 : a0;
      const int bB = ks ? b1 : b0;
      bf16x8 ah[4], al[4];
#pragma unroll
      for (int m = 0; m < 4; ++m) {
        ah[m] = *reinterpret_cast<const bf16x8*>(smem +         aB + m * 2048);
        al[m] = *reinterpret_cast<const bf16x8*>(smem + 16384 + aB + m * 2048);
      }
#pragma unroll
      for (int n = 0; n < 4; ++n) {
        bf16x8 bh = *reinterpret_cast<const bf16x8*>(smem + 32768 + bB + n * 2048);
        bf16x8 bl = *reinterpret_cast<const bf16x8*>(smem + 49152 + bB + n * 2048);
#pragma unroll
        for (int m = 0; m < 4; ++m) {
          acc[m][n] = __builtin_amdgcn_mfma_f32_16x16x32_bf16(ah[m], bh, acc[m][n], 0, 0, 0);
          acc[m][n] = __builtin_amdgcn_mfma_f32_16x16x32_bf16(ah[m], bl, acc[m][n], 0, 0, 0);
          acc[m][n] = __builtin_amdgcn_mfma_f32_16x16x32_bf16(al[m], bh, acc[m][n], 0, 0, 0);
        }
      }
    }
    __syncthreads();
  }

  // epilogue: out[tok][gc] += wt * (acc + bias)   (exactly 2 atomics per out elem)
  int   tk[16];
  float wt[16];
  const int q4 = (l >> 4) * 4;
#pragma unroll
  for (int m = 0; m < 4; ++m)
#pragma unroll
    for (int q = 0; q < 4; ++q) {
      int r  = wr * 64 + m * 16 + q4 + q;
      int rg = bx * 128 + r;
      bool v = rg < ce;
      tk[m * 4 + q] = v ? tok_list[e * T_TOK + rg] : 0;
      wt[m * 4 + q] = v ? tok_w[e * T_TOK + rg] : 0.0f;   // pad rows contribute 0
    }
#pragma unroll
  for (int n = 0; n < 4; ++n) {
    const int gc = by * 128 + wc * 64 + n * 16 + (l & 15);
    const float bias = eb[e * OUTD + gc];
#pragma unroll
    for (int m = 0; m < 4; ++m)
#pragma unroll
      for (int q = 0; q < 4; ++q) {
        float val = wt[m * 4 + q] * (acc[m][n][q] + bias);
        atomicAdd(out + (size_t)tk[m * 4 + q] * OUTD + gc, val);
      }
  }
}

extern "C" void kernel_launch(void* const* d_in, const int* in_sizes, int n_in,
                              void* d_out, int out_size, void* d_ws, size_t ws_size,
                              hipStream_t stream) {
  const float* x  = (const float*)d_in[0];   // [2,4096,2048]
  const float* gw = (const float*)d_in[1];   // [8,2048]
  const float* ew = (const float*)d_in[2];   // [8,2048,2048]
  const float* eb = (const float*)d_in[3];   // [8,2048]
  float* out = (float*)d_out;                // [2,4096,2048]

  char* ws = (char*)d_ws;
  int*   cnt      = (int*)(ws);                          // 32 B (pad 256)
  int*   tok_list = (int*)(ws + 256);                    // 8*8192*4 = 256 KiB
  float* tok_w    = (float*)(ws + 256 + 262144);         // 256 KiB
  unsigned short* xh = (unsigned short*)(ws + 524544);   // 32 MiB
  unsigned short* xl = xh + 16777216;                    // 32 MiB
  unsigned short* wh = xl + 16777216;                    // 64 MiB
  unsigned short* wl = wh + 33554432;                    // 64 MiB

  hipMemsetAsync(cnt, 0, 256, stream);
  hipMemsetAsync(d_out, 0, (size_t)out_size * sizeof(float), stream);

  split_hi_lo<<<4096, 256, 0, stream>>>(x,  xh, xl, 16777216 / 4);
  split_hi_lo<<<4096, 256, 0, stream>>>(ew, wh, wl, 33554432 / 4);
  router<<<T_TOK / 4, 256, 0, stream>>>(x, gw, cnt, tok_list, tok_w);

  // worst case: one expert owns all 8192 tokens -> 64 row-blocks; inactive exit early
  moe_gemm<<<dim3(64, 16, 8), 256, 65536, stream>>>(xh, xl, wh, wl, eb, cnt,
                                                    tok_list, tok_w, out);
}